// Round 1
// baseline (29425.992 us; speedup 1.0000x reference)
//
#include <hip/hip_runtime.h>

// Llama-style forward: B=2,T=1024, D=768, H=12,HS=64, NKV=3 (GQA rep 4),
// L=12, I=2048, V=50257. idx int32, output fp32 logits (B,T,V).
// GEMMs use split-bf16 (hi/lo truncation) 3-term MFMA:
//   a*b ~= ah*bh + ah*bl + al*bh, per-product rel err ~3*2^-16 (fp32-grade).

#define NTOK 2048      // B*T
#define DM   768
#define DKV  192       // NKV*HS
#define TSEQ 1024
#define NH   12
#define HSZ  64
#define NKVH 3
#define IDIM 2048
#define VOC  50257
#define NLAY 12

typedef __attribute__((ext_vector_type(8))) short short8;   // 8 bf16 (4 VGPR)
typedef __attribute__((ext_vector_type(4))) float f32x4;    // MFMA acc

// ---------------- embedding gather ----------------
__global__ void embed_kernel(const int* __restrict__ idx,
                             const float* __restrict__ embed,
                             float* __restrict__ x) {
    int tok = blockIdx.x;
    int row = idx[tok];
    for (int d = threadIdx.x; d < DM; d += 256)
        x[(size_t)tok * DM + d] = embed[(size_t)row * DM + d];
}

// ---------------- RMSNorm ----------------
__global__ void rmsnorm_kernel(const float* __restrict__ x,
                               const float* __restrict__ w,
                               float* __restrict__ o) {
    int tok = blockIdx.x;
    const float* xr = x + (size_t)tok * DM;
    float ss = 0.f;
    for (int d = threadIdx.x; d < DM; d += 256) { float v = xr[d]; ss += v * v; }
    __shared__ float red[256];
    red[threadIdx.x] = ss;
    __syncthreads();
    for (int s = 128; s > 0; s >>= 1) {
        if (threadIdx.x < s) red[threadIdx.x] += red[threadIdx.x + s];
        __syncthreads();
    }
    float rs = rsqrtf(red[0] / (float)DM + 1e-6f);
    for (int d = threadIdx.x; d < DM; d += 256)
        o[(size_t)tok * DM + d] = xr[d] * rs * w[d];
}

// pack the high 16 bits (bf16 truncation) of two fp32 into one u32:
// result = { bf16(e0) in [15:0], bf16(e1) in [31:16] }
__device__ __forceinline__ unsigned pack_hi(unsigned e0, unsigned e1) {
    return __builtin_amdgcn_perm(e1, e0, 0x07060302u);
}

// ---------------- GEMM: C[M,N] = A[M,K] * B (+C), fp32 in/out ----------------
// Split-bf16 MFMA: 128x128 block tile, 4 waves of 64x64, K-step 32,
// v_mfma_f32_16x16x32_bf16. A row-major [M,K]; BT=false: B row-major [K,N];
// BT=true: B row-major [N,K]. M % 128 == 0, K % 32 == 0; N guarded.
template<bool RES, bool BT>
__global__ void gemm_kernel(const float* __restrict__ A,
                            const float* __restrict__ B,
                            float* __restrict__ C, int M, int N, int K) {
    // row stride 40 shorts (80 B): 16B-aligned rows, ~2-way banked frag reads
    __shared__ short Ah[128][40];
    __shared__ short Al[128][40];
    __shared__ short Bh[128][40];   // stored as [n][k]
    __shared__ short Bl[128][40];

    const int t    = threadIdx.x;
    const int m0   = blockIdx.y * 128;
    const int n0   = blockIdx.x * 128;
    const int lane = t & 63, w = t >> 6;
    const int wr   = w >> 1, wc = w & 1;        // wave = 64x64 sub-tile
    const int lr   = lane & 15;                 // fragment row/col
    const int lk   = (lane >> 4) * 8;           // fragment k-octet (shorts)

    f32x4 acc[4][4] = {};

    for (int k0 = 0; k0 < K; k0 += 32) {
        // ---- stage A tile (128 x 32 fp32 -> bf16 hi/lo) ----
#pragma unroll
        for (int i = 0; i < 4; i++) {
            int g = t + 256 * i;                 // 0..1023
            int row = g >> 3, kq = g & 7;
            float4 av = *(const float4*)&A[(size_t)(m0 + row) * K + k0 + kq * 4];
            unsigned b0 = __float_as_uint(av.x), b1 = __float_as_uint(av.y);
            unsigned b2 = __float_as_uint(av.z), b3 = __float_as_uint(av.w);
            float l0 = av.x - __uint_as_float(b0 & 0xFFFF0000u);
            float l1 = av.y - __uint_as_float(b1 & 0xFFFF0000u);
            float l2 = av.z - __uint_as_float(b2 & 0xFFFF0000u);
            float l3 = av.w - __uint_as_float(b3 & 0xFFFF0000u);
            *(uint2*)&Ah[row][kq * 4] = make_uint2(pack_hi(b0, b1), pack_hi(b2, b3));
            *(uint2*)&Al[row][kq * 4] =
                make_uint2(pack_hi(__float_as_uint(l0), __float_as_uint(l1)),
                           pack_hi(__float_as_uint(l2), __float_as_uint(l3)));
        }
        // ---- stage B tile ----
        if (BT) {
            // B is [N,K] row-major: same fast path as A (b64 LDS writes)
#pragma unroll
            for (int i = 0; i < 4; i++) {
                int g = t + 256 * i;
                int row = g >> 3, kq = g & 7;
                int n = n0 + row;
                float4 bv = make_float4(0.f, 0.f, 0.f, 0.f);
                if (n < N) bv = *(const float4*)&B[(size_t)n * K + k0 + kq * 4];
                unsigned b0 = __float_as_uint(bv.x), b1 = __float_as_uint(bv.y);
                unsigned b2 = __float_as_uint(bv.z), b3 = __float_as_uint(bv.w);
                float l0 = bv.x - __uint_as_float(b0 & 0xFFFF0000u);
                float l1 = bv.y - __uint_as_float(b1 & 0xFFFF0000u);
                float l2 = bv.z - __uint_as_float(b2 & 0xFFFF0000u);
                float l3 = bv.w - __uint_as_float(b3 & 0xFFFF0000u);
                *(uint2*)&Bh[row][kq * 4] = make_uint2(pack_hi(b0, b1), pack_hi(b2, b3));
                *(uint2*)&Bl[row][kq * 4] =
                    make_uint2(pack_hi(__float_as_uint(l0), __float_as_uint(l1)),
                               pack_hi(__float_as_uint(l2), __float_as_uint(l3)));
            }
        } else {
            // B is [K,N] row-major: coalesced float4 along N, transposed store
#pragma unroll
            for (int i = 0; i < 4; i++) {
                int g = t + 256 * i;
                int kk = g >> 5, nq = g & 31;
                int n = n0 + nq * 4;
                float4 bv = (n < N) ? *(const float4*)&B[(size_t)(k0 + kk) * N + n]
                                    : make_float4(0.f, 0.f, 0.f, 0.f);
                float el[4] = {bv.x, bv.y, bv.z, bv.w};
#pragma unroll
                for (int e = 0; e < 4; e++) {
                    unsigned b = __float_as_uint(el[e]);
                    float lo = el[e] - __uint_as_float(b & 0xFFFF0000u);
                    Bh[nq * 4 + e][kk] = (short)(b >> 16);
                    Bl[nq * 4 + e][kk] = (short)(__float_as_uint(lo) >> 16);
                }
            }
        }
        __syncthreads();

        // ---- fragments (ds_read_b128) + 3-term MFMA ----
        short8 ah[4], al[4], bh[4], bl[4];
#pragma unroll
        for (int mi = 0; mi < 4; mi++) {
            int r = wr * 64 + mi * 16 + lr;
            ah[mi] = *(const short8*)&Ah[r][lk];
            al[mi] = *(const short8*)&Al[r][lk];
        }
#pragma unroll
        for (int ni = 0; ni < 4; ni++) {
            int r = wc * 64 + ni * 16 + lr;
            bh[ni] = *(const short8*)&Bh[r][lk];
            bl[ni] = *(const short8*)&Bl[r][lk];
        }
#pragma unroll
        for (int mi = 0; mi < 4; mi++)
#pragma unroll
            for (int ni = 0; ni < 4; ni++) {
                f32x4 c = acc[mi][ni];
                c = __builtin_amdgcn_mfma_f32_16x16x32_bf16(ah[mi], bh[ni], c, 0, 0, 0);
                c = __builtin_amdgcn_mfma_f32_16x16x32_bf16(ah[mi], bl[ni], c, 0, 0, 0);
                c = __builtin_amdgcn_mfma_f32_16x16x32_bf16(al[mi], bh[ni], c, 0, 0, 0);
                acc[mi][ni] = c;
            }
        __syncthreads();
    }

    // ---- store: C/D layout col=lane&15, row=(lane>>4)*4+reg ----
    const int cr = (lane >> 4) * 4, cc = lane & 15;
#pragma unroll
    for (int mi = 0; mi < 4; mi++) {
#pragma unroll
        for (int ni = 0; ni < 4; ni++) {
            int gr = m0 + wr * 64 + mi * 16 + cr;
            int gc = n0 + wc * 64 + ni * 16 + cc;
            if (gc < N) {
#pragma unroll
                for (int r = 0; r < 4; r++) {
                    size_t o = (size_t)(gr + r) * N + gc;
                    float v = acc[mi][ni][r];
                    if (RES) v += C[o];
                    C[o] = v;
                }
            }
        }
    }
}

// ---------------- RoPE (rotate-half, half=32, full head dim 64) ----------------
__global__ void rope_kernel(float* __restrict__ p, int nheads, int total) {
    int gid = blockIdx.x * 256 + threadIdx.x;
    if (gid >= total) return;
    int j    = gid & 31;
    int rest = gid >> 5;
    int h    = rest % nheads;
    int tok  = rest / nheads;
    int pos  = tok & (TSEQ - 1);
    float freq = powf(10000.f, (float)j * (1.f / 32.f));
    float ang  = (float)pos / freq;
    float s = sinf(ang), c = cosf(ang);
    float* row = p + (size_t)tok * (nheads * HSZ) + h * HSZ;
    float a = row[j], b = row[j + 32];
    row[j]      = a * c - b * s;
    row[j + 32] = b * c + a * s;
}

// ---------------- causal attention, online softmax ----------------
__global__ void attn_kernel(const float* __restrict__ q,
                            const float* __restrict__ k,
                            const float* __restrict__ v,
                            float* __restrict__ y) {
    int lane = threadIdx.x & 63;
    int wv   = threadIdx.x >> 6;
    int row  = blockIdx.x * 4 + wv;          // [0, B*H*T)
    int tq   = row & (TSEQ - 1);
    int h    = (row >> 10) % NH;
    int b    = row / (TSEQ * NH);
    int kvh  = h % NKVH;
    size_t tok = (size_t)b * TSEQ + tq;
    float qd = q[tok * DM + h * HSZ + lane] * 0.125f;   // 1/sqrt(64)
    const float* kb = k + (size_t)b * TSEQ * DKV + kvh * HSZ + lane;
    const float* vb = v + (size_t)b * TSEQ * DKV + kvh * HSZ + lane;
    float m = -3.0e38f, l = 0.f, acc = 0.f;
    for (int j = 0; j <= tq; j++) {
        float s = qd * kb[(size_t)j * DKV];
#pragma unroll
        for (int off = 32; off; off >>= 1) s += __shfl_xor(s, off, 64);
        float mn   = fmaxf(m, s);
        float corr = expf(m - mn);
        float p    = expf(s - mn);
        l   = l * corr + p;
        acc = acc * corr + p * vb[(size_t)j * DKV];
        m = mn;
    }
    y[tok * DM + h * HSZ + lane] = acc / l;
}

// ---------------- SwiGLU elementwise ----------------
__global__ void silu_mul_kernel(float* __restrict__ g,
                                const float* __restrict__ u, int n) {
    int i = blockIdx.x * 256 + threadIdx.x;
    if (i < n) {
        float x = g[i];
        g[i] = (x / (1.f + expf(-x))) * u[i];
    }
}

extern "C" void kernel_launch(void* const* d_in, const int* in_sizes, int n_in,
                              void* d_out, int out_size, void* d_ws, size_t ws_size,
                              hipStream_t stream) {
    const int*   idx    = (const int*)d_in[0];
    const float* embed  = (const float*)d_in[1];
    const float* ln1_w  = (const float*)d_in[2];
    const float* q_w    = (const float*)d_in[3];
    const float* k_w    = (const float*)d_in[4];
    const float* v_w    = (const float*)d_in[5];
    const float* o_w    = (const float*)d_in[6];
    const float* ln2_w  = (const float*)d_in[7];
    const float* gate_w = (const float*)d_in[8];
    const float* up_w   = (const float*)d_in[9];
    const float* down_w = (const float*)d_in[10];
    const float* norm_w = (const float*)d_in[11];
    float* out = (float*)d_out;

    float* x  = (float*)d_ws;                 // NTOK*DM
    float* h  = x  + (size_t)NTOK * DM;       // NTOK*DM
    float* qb = h  + (size_t)NTOK * DM;       // NTOK*DM
    float* kb = qb + (size_t)NTOK * DM;       // NTOK*DKV
    float* vb = kb + (size_t)NTOK * DKV;      // NTOK*DKV
    float* yb = vb + (size_t)NTOK * DKV;      // NTOK*DM
    // MLP buffers alias the attention buffers (disjoint in time):
    float* gb = qb;                           // NTOK*IDIM
    float* ub = qb + (size_t)NTOK * IDIM;     // NTOK*IDIM

    dim3 blk(256);
    embed_kernel<<<NTOK, blk, 0, stream>>>(idx, embed, x);
    for (int l = 0; l < NLAY; l++) {
        rmsnorm_kernel<<<NTOK, blk, 0, stream>>>(x, ln1_w + (size_t)l * DM, h);
        gemm_kernel<false,false><<<dim3(DM/128,          NTOK/128), blk, 0, stream>>>(h, q_w + (size_t)l*DM*DM,  qb, NTOK, DM,  DM);
        gemm_kernel<false,false><<<dim3((DKV+127)/128,   NTOK/128), blk, 0, stream>>>(h, k_w + (size_t)l*DM*DKV, kb, NTOK, DKV, DM);
        gemm_kernel<false,false><<<dim3((DKV+127)/128,   NTOK/128), blk, 0, stream>>>(h, v_w + (size_t)l*DM*DKV, vb, NTOK, DKV, DM);
        rope_kernel<<<(NTOK*NH*32   + 255)/256, blk, 0, stream>>>(qb, NH,   NTOK*NH*32);
        rope_kernel<<<(NTOK*NKVH*32 + 255)/256, blk, 0, stream>>>(kb, NKVH, NTOK*NKVH*32);
        attn_kernel<<<NTOK*NH/4, blk, 0, stream>>>(qb, kb, vb, yb);
        gemm_kernel<true,false><<<dim3(DM/128,  NTOK/128), blk, 0, stream>>>(yb, o_w + (size_t)l*DM*DM, x, NTOK, DM, DM);
        rmsnorm_kernel<<<NTOK, blk, 0, stream>>>(x, ln2_w + (size_t)l * DM, h);
        gemm_kernel<false,false><<<dim3(IDIM/128, NTOK/128), blk, 0, stream>>>(h, gate_w + (size_t)l*DM*IDIM, gb, NTOK, IDIM, DM);
        gemm_kernel<false,false><<<dim3(IDIM/128, NTOK/128), blk, 0, stream>>>(h, up_w   + (size_t)l*DM*IDIM, ub, NTOK, IDIM, DM);
        silu_mul_kernel<<<(NTOK*IDIM + 255)/256, blk, 0, stream>>>(gb, ub, NTOK*IDIM);
        gemm_kernel<true,false><<<dim3(DM/128, NTOK/128), blk, 0, stream>>>(gb, down_w + (size_t)l*IDIM*DM, x, NTOK, DM, IDIM);
    }
    rmsnorm_kernel<<<NTOK, blk, 0, stream>>>(x, norm_w, h);
    gemm_kernel<false,true><<<dim3((VOC+127)/128, NTOK/128), blk, 0, stream>>>(h, embed, out, NTOK, VOC, DM);
}

// Round 2
// 10250.441 us; speedup vs baseline: 2.8707x; 2.8707x over previous
//
#include <hip/hip_runtime.h>

// Llama-style forward: B=2,T=1024, D=768, H=12,HS=64, NKV=3 (GQA rep 4),
// L=12, I=2048, V=50257. idx int32, output fp32 logits (B,T,V).
// GEMMs: split-bf16 (hi/lo truncation) 3-term MFMA (fp32-grade accuracy).
// Attention: flash-style bf16 MFMA (QK^T and PV on matrix cores, RNE cvt).

#define NTOK 2048      // B*T
#define DM   768
#define DKV  192       // NKV*HS
#define TSEQ 1024
#define NH   12
#define HSZ  64
#define NKVH 3
#define IDIM 2048
#define VOC  50257
#define NLAY 12

typedef __attribute__((ext_vector_type(8))) short short8;   // 8 bf16 (4 VGPR)
typedef __attribute__((ext_vector_type(4))) float f32x4;    // MFMA acc

// bf16 round-to-nearest-even
__device__ __forceinline__ unsigned short bf16rne(float x) {
    unsigned u = __float_as_uint(x);
    unsigned r = u + 0x7FFFu + ((u >> 16) & 1u);
    return (unsigned short)(r >> 16);
}

// pack the high 16 bits (bf16 truncation) of two fp32 into one u32
__device__ __forceinline__ unsigned pack_hi(unsigned e0, unsigned e1) {
    return __builtin_amdgcn_perm(e1, e0, 0x07060302u);
}

// ---------------- embedding gather ----------------
__global__ void embed_kernel(const int* __restrict__ idx,
                             const float* __restrict__ embed,
                             float* __restrict__ x) {
    int tok = blockIdx.x;
    int row = idx[tok];
    for (int d = threadIdx.x; d < DM; d += 256)
        x[(size_t)tok * DM + d] = embed[(size_t)row * DM + d];
}

// ---------------- RMSNorm ----------------
__global__ void rmsnorm_kernel(const float* __restrict__ x,
                               const float* __restrict__ w,
                               float* __restrict__ o) {
    int tok = blockIdx.x;
    const float* xr = x + (size_t)tok * DM;
    float ss = 0.f;
    for (int d = threadIdx.x; d < DM; d += 256) { float v = xr[d]; ss += v * v; }
    __shared__ float red[256];
    red[threadIdx.x] = ss;
    __syncthreads();
    for (int s = 128; s > 0; s >>= 1) {
        if (threadIdx.x < s) red[threadIdx.x] += red[threadIdx.x + s];
        __syncthreads();
    }
    float rs = rsqrtf(red[0] / (float)DM + 1e-6f);
    for (int d = threadIdx.x; d < DM; d += 256)
        o[(size_t)tok * DM + d] = xr[d] * rs * w[d];
}

// ============ head GEMM (BM=128, B transposed [N,K]) ============
// C[M,N] = A[M,K] * B^T. M%128==0, K%32==0, N guarded.
__global__ void gemm_head_kernel(const float* __restrict__ A,
                                 const float* __restrict__ B,
                                 float* __restrict__ C, int M, int N, int K) {
    __shared__ short Ah[128][40];
    __shared__ short Al[128][40];
    __shared__ short Bh[128][40];   // [n][k]
    __shared__ short Bl[128][40];

    const int t    = threadIdx.x;
    const int m0   = blockIdx.y * 128;
    const int n0   = blockIdx.x * 128;
    const int lane = t & 63, w = t >> 6;
    const int wr   = w >> 1, wc = w & 1;
    const int lr   = lane & 15;
    const int lk   = (lane >> 4) * 8;

    f32x4 acc[4][4] = {};

    for (int k0 = 0; k0 < K; k0 += 32) {
#pragma unroll
        for (int i = 0; i < 4; i++) {
            int g = t + 256 * i;
            int row = g >> 3, kq = g & 7;
            float4 av = *(const float4*)&A[(size_t)(m0 + row) * K + k0 + kq * 4];
            unsigned b0 = __float_as_uint(av.x), b1 = __float_as_uint(av.y);
            unsigned b2 = __float_as_uint(av.z), b3 = __float_as_uint(av.w);
            float l0 = av.x - __uint_as_float(b0 & 0xFFFF0000u);
            float l1 = av.y - __uint_as_float(b1 & 0xFFFF0000u);
            float l2 = av.z - __uint_as_float(b2 & 0xFFFF0000u);
            float l3 = av.w - __uint_as_float(b3 & 0xFFFF0000u);
            *(uint2*)&Ah[row][kq * 4] = make_uint2(pack_hi(b0, b1), pack_hi(b2, b3));
            *(uint2*)&Al[row][kq * 4] =
                make_uint2(pack_hi(__float_as_uint(l0), __float_as_uint(l1)),
                           pack_hi(__float_as_uint(l2), __float_as_uint(l3)));
        }
#pragma unroll
        for (int i = 0; i < 4; i++) {
            int g = t + 256 * i;
            int row = g >> 3, kq = g & 7;
            int n = n0 + row;
            float4 bv = make_float4(0.f, 0.f, 0.f, 0.f);
            if (n < N) bv = *(const float4*)&B[(size_t)n * K + k0 + kq * 4];
            unsigned b0 = __float_as_uint(bv.x), b1 = __float_as_uint(bv.y);
            unsigned b2 = __float_as_uint(bv.z), b3 = __float_as_uint(bv.w);
            float l0 = bv.x - __uint_as_float(b0 & 0xFFFF0000u);
            float l1 = bv.y - __uint_as_float(b1 & 0xFFFF0000u);
            float l2 = bv.z - __uint_as_float(b2 & 0xFFFF0000u);
            float l3 = bv.w - __uint_as_float(b3 & 0xFFFF0000u);
            *(uint2*)&Bh[row][kq * 4] = make_uint2(pack_hi(b0, b1), pack_hi(b2, b3));
            *(uint2*)&Bl[row][kq * 4] =
                make_uint2(pack_hi(__float_as_uint(l0), __float_as_uint(l1)),
                           pack_hi(__float_as_uint(l2), __float_as_uint(l3)));
        }
        __syncthreads();

        short8 ah[4], al[4], bh[4], bl[4];
#pragma unroll
        for (int mi = 0; mi < 4; mi++) {
            int r = wr * 64 + mi * 16 + lr;
            ah[mi] = *(const short8*)&Ah[r][lk];
            al[mi] = *(const short8*)&Al[r][lk];
        }
#pragma unroll
        for (int ni = 0; ni < 4; ni++) {
            int r = wc * 64 + ni * 16 + lr;
            bh[ni] = *(const short8*)&Bh[r][lk];
            bl[ni] = *(const short8*)&Bl[r][lk];
        }
#pragma unroll
        for (int mi = 0; mi < 4; mi++)
#pragma unroll
            for (int ni = 0; ni < 4; ni++) {
                f32x4 cacc = acc[mi][ni];
                cacc = __builtin_amdgcn_mfma_f32_16x16x32_bf16(ah[mi], bh[ni], cacc, 0, 0, 0);
                cacc = __builtin_amdgcn_mfma_f32_16x16x32_bf16(ah[mi], bl[ni], cacc, 0, 0, 0);
                cacc = __builtin_amdgcn_mfma_f32_16x16x32_bf16(al[mi], bh[ni], cacc, 0, 0, 0);
                acc[mi][ni] = cacc;
            }
        __syncthreads();
    }

    const int cr = (lane >> 4) * 4, cc = lane & 15;
#pragma unroll
    for (int mi = 0; mi < 4; mi++) {
#pragma unroll
        for (int ni = 0; ni < 4; ni++) {
            int gr = m0 + wr * 64 + mi * 16 + cr;
            int gc = n0 + wc * 64 + ni * 16 + cc;
            if (gc < N) {
#pragma unroll
                for (int r = 0; r < 4; r++)
                    C[(size_t)(gr + r) * N + gc] = acc[mi][ni][r];
            }
        }
    }
}

// ============ layer GEMM (BM=64, BN=128), multi-range fused ============
// Up to 3 output ranges share the same A: blockIdx.x selects (B,C,N) range.
// B row-major [K,N]. M%64==0, K%32==0, N guarded per range.
template<bool RES>
__global__ void gemm64_kernel(const float* __restrict__ A,
                              const float* __restrict__ B0, const float* __restrict__ B1,
                              const float* __restrict__ B2,
                              float* __restrict__ C0, float* __restrict__ C1,
                              float* __restrict__ C2,
                              int M, int K, int N0, int N1, int N2,
                              int nb0, int nb1) {
    __shared__ short Ah[64][40];
    __shared__ short Al[64][40];
    __shared__ short Bh[128][40];   // [n][k]
    __shared__ short Bl[128][40];

    const int t  = threadIdx.x;
    const int nb = blockIdx.x;
    const float* B; float* C; int N; int nloc;
    if (nb < nb0)            { B = B0; C = C0; N = N0; nloc = nb; }
    else if (nb < nb0 + nb1) { B = B1; C = C1; N = N1; nloc = nb - nb0; }
    else                     { B = B2; C = C2; N = N2; nloc = nb - nb0 - nb1; }
    const int n0 = nloc * 128;
    const int m0 = blockIdx.y * 64;
    const int lane = t & 63, w = t >> 6;
    const int wr   = w >> 1, wc = w & 1;        // wave = 32x64 sub-tile
    const int lr   = lane & 15;
    const int lk   = (lane >> 4) * 8;

    f32x4 acc[2][4] = {};

    for (int k0 = 0; k0 < K; k0 += 32) {
        // A tile: 64x32 fp32 -> bf16 hi/lo
#pragma unroll
        for (int i = 0; i < 2; i++) {
            int g = t + 256 * i;                 // 0..511
            int row = g >> 3, kq = g & 7;
            float4 av = *(const float4*)&A[(size_t)(m0 + row) * K + k0 + kq * 4];
            unsigned b0 = __float_as_uint(av.x), b1 = __float_as_uint(av.y);
            unsigned b2 = __float_as_uint(av.z), b3 = __float_as_uint(av.w);
            float l0 = av.x - __uint_as_float(b0 & 0xFFFF0000u);
            float l1 = av.y - __uint_as_float(b1 & 0xFFFF0000u);
            float l2 = av.z - __uint_as_float(b2 & 0xFFFF0000u);
            float l3 = av.w - __uint_as_float(b3 & 0xFFFF0000u);
            *(uint2*)&Ah[row][kq * 4] = make_uint2(pack_hi(b0, b1), pack_hi(b2, b3));
            *(uint2*)&Al[row][kq * 4] =
                make_uint2(pack_hi(__float_as_uint(l0), __float_as_uint(l1)),
                           pack_hi(__float_as_uint(l2), __float_as_uint(l3)));
        }
        // B tile: 32k x 128n, coalesced along N, transposed store to [n][k]
#pragma unroll
        for (int i = 0; i < 4; i++) {
            int g = t + 256 * i;
            int kk = g >> 5, nq = g & 31;
            int n = n0 + nq * 4;
            float4 bv = (n < N) ? *(const float4*)&B[(size_t)(k0 + kk) * N + n]
                                : make_float4(0.f, 0.f, 0.f, 0.f);
            float el[4] = {bv.x, bv.y, bv.z, bv.w};
#pragma unroll
            for (int e = 0; e < 4; e++) {
                unsigned bu = __float_as_uint(el[e]);
                float lo = el[e] - __uint_as_float(bu & 0xFFFF0000u);
                Bh[nq * 4 + e][kk] = (short)(bu >> 16);
                Bl[nq * 4 + e][kk] = (short)(__float_as_uint(lo) >> 16);
            }
        }
        __syncthreads();

        short8 ah[2], al[2], bh[4], bl[4];
#pragma unroll
        for (int mi = 0; mi < 2; mi++) {
            int r = wr * 32 + mi * 16 + lr;
            ah[mi] = *(const short8*)&Ah[r][lk];
            al[mi] = *(const short8*)&Al[r][lk];
        }
#pragma unroll
        for (int ni = 0; ni < 4; ni++) {
            int r = wc * 64 + ni * 16 + lr;
            bh[ni] = *(const short8*)&Bh[r][lk];
            bl[ni] = *(const short8*)&Bl[r][lk];
        }
#pragma unroll
        for (int mi = 0; mi < 2; mi++)
#pragma unroll
            for (int ni = 0; ni < 4; ni++) {
                f32x4 cacc = acc[mi][ni];
                cacc = __builtin_amdgcn_mfma_f32_16x16x32_bf16(ah[mi], bh[ni], cacc, 0, 0, 0);
                cacc = __builtin_amdgcn_mfma_f32_16x16x32_bf16(ah[mi], bl[ni], cacc, 0, 0, 0);
                cacc = __builtin_amdgcn_mfma_f32_16x16x32_bf16(al[mi], bh[ni], cacc, 0, 0, 0);
                acc[mi][ni] = cacc;
            }
        __syncthreads();
    }

    const int cr = (lane >> 4) * 4, cc = lane & 15;
#pragma unroll
    for (int mi = 0; mi < 2; mi++) {
#pragma unroll
        for (int ni = 0; ni < 4; ni++) {
            int gr = m0 + wr * 32 + mi * 16 + cr;
            int gc = n0 + wc * 64 + ni * 16 + cc;
            if (gc < N) {
#pragma unroll
                for (int r = 0; r < 4; r++) {
                    size_t o = (size_t)(gr + r) * N + gc;
                    float v = acc[mi][ni][r];
                    if (RES) v += C[o];
                    C[o] = v;
                }
            }
        }
    }
}

// ---------------- RoPE (rotate-half, half=32, full head dim 64) ----------------
__global__ void rope_kernel(float* __restrict__ p, int nheads, int total) {
    int gid = blockIdx.x * 256 + threadIdx.x;
    if (gid >= total) return;
    int j    = gid & 31;
    int rest = gid >> 5;
    int h    = rest % nheads;
    int tok  = rest / nheads;
    int pos  = tok & (TSEQ - 1);
    float freq = powf(10000.f, (float)j * (1.f / 32.f));
    float ang  = (float)pos / freq;
    float s = sinf(ang), c = cosf(ang);
    float* row = p + (size_t)tok * (nheads * HSZ) + h * HSZ;
    float a = row[j], b = row[j + 32];
    row[j]      = a * c - b * s;
    row[j + 32] = b * c + a * s;
}

// ---------------- flash attention: MFMA QK^T + PV, online softmax ----------------
// Block = 4 waves; block handles (b,h) x 64-query tile; wave owns 16 queries.
// KV tiles of 32 keys staged in LDS as bf16 (K row-major, V transposed).
__global__ void attn_kernel(const float* __restrict__ q,
                            const float* __restrict__ k,
                            const float* __restrict__ v,
                            float* __restrict__ y) {
    __shared__ short Ks[32][72];      // [key][d]   (+8 pad: 2-way banked b128)
    __shared__ short Vt[64][40];      // [d][key]   (+8 pad)
    __shared__ short Ps[4][16][40];   // per-wave P transpose scratch [q][key]

    const int t = threadIdx.x, lane = t & 63, w = t >> 6;
    const int qt = blockIdx.x & 15;              // TSEQ/64
    const int h  = (blockIdx.x >> 4) % NH;
    const int b  = blockIdx.x / (16 * NH);
    const int q0 = qt * 64;
    const int wq0 = q0 + w * 16;                 // wave's first query
    const int kvh = h % NKVH;
    const int g = lane >> 4, c = lane & 15;

    // Q A-fragments (row = c, k-octet = g*8), softmax scale folded in
    short8 qf[2];
    {
        const float* qr = q + ((size_t)b * TSEQ + wq0 + c) * DM + h * HSZ + g * 8;
#pragma unroll
        for (int dh = 0; dh < 2; dh++) {
            float4 a0 = *(const float4*)(qr + dh * 32);
            float4 a1 = *(const float4*)(qr + dh * 32 + 4);
            short8 s8;
            s8[0] = (short)bf16rne(a0.x * 0.125f);
            s8[1] = (short)bf16rne(a0.y * 0.125f);
            s8[2] = (short)bf16rne(a0.z * 0.125f);
            s8[3] = (short)bf16rne(a0.w * 0.125f);
            s8[4] = (short)bf16rne(a1.x * 0.125f);
            s8[5] = (short)bf16rne(a1.y * 0.125f);
            s8[6] = (short)bf16rne(a1.z * 0.125f);
            s8[7] = (short)bf16rne(a1.w * 0.125f);
            qf[dh] = s8;
        }
    }

    f32x4 po[4] = {};                            // O acc, C layout per d-block
    float m_[4] = {-3.0e38f, -3.0e38f, -3.0e38f, -3.0e38f};
    float l_[4] = {};

    const int kmax = q0 + 63;
    for (int k0 = 0; k0 <= kmax; k0 += 32) {
        // ---- cooperative staging: K[32][64] and Vt[64][32], fp32->bf16 ----
        {
            int kr = t >> 3, kq = t & 7;
            const float* kp = k + ((size_t)b * TSEQ + k0 + kr) * DKV + kvh * HSZ + kq * 8;
            float4 b0 = *(const float4*)kp;
            float4 b1 = *(const float4*)(kp + 4);
            short8 s8;
            s8[0] = (short)bf16rne(b0.x); s8[1] = (short)bf16rne(b0.y);
            s8[2] = (short)bf16rne(b0.z); s8[3] = (short)bf16rne(b0.w);
            s8[4] = (short)bf16rne(b1.x); s8[5] = (short)bf16rne(b1.y);
            s8[6] = (short)bf16rne(b1.z); s8[7] = (short)bf16rne(b1.w);
            *(short8*)&Ks[kr][kq * 8] = s8;

            int vk = t & 31, dq = t >> 5;
            const float* vp = v + ((size_t)b * TSEQ + k0 + vk) * DKV + kvh * HSZ + dq * 8;
            float4 c0 = *(const float4*)vp;
            float4 c1 = *(const float4*)(vp + 4);
            Vt[dq * 8 + 0][vk] = (short)bf16rne(c0.x);
            Vt[dq * 8 + 1][vk] = (short)bf16rne(c0.y);
            Vt[dq * 8 + 2][vk] = (short)bf16rne(c0.z);
            Vt[dq * 8 + 3][vk] = (short)bf16rne(c0.w);
            Vt[dq * 8 + 4][vk] = (short)bf16rne(c1.x);
            Vt[dq * 8 + 5][vk] = (short)bf16rne(c1.y);
            Vt[dq * 8 + 6][vk] = (short)bf16rne(c1.z);
            Vt[dq * 8 + 7][vk] = (short)bf16rne(c1.w);
        }
        __syncthreads();

        if (k0 <= wq0 + 15) {                    // wave has unmasked work
            // ---- S = Q K^T : two 16-key blocks, K-dim 64 = 2 MFMAs each ----
            f32x4 s[2];
#pragma unroll
            for (int kb = 0; kb < 2; kb++) {
                short8 kf0 = *(const short8*)&Ks[kb * 16 + c][g * 8];
                short8 kf1 = *(const short8*)&Ks[kb * 16 + c][32 + g * 8];
                f32x4 a = {};
                a = __builtin_amdgcn_mfma_f32_16x16x32_bf16(qf[0], kf0, a, 0, 0, 0);
                a = __builtin_amdgcn_mfma_f32_16x16x32_bf16(qf[1], kf1, a, 0, 0, 0);
                s[kb] = a;
            }
            // causal mask (only boundary tiles hit this)
            if (k0 + 31 > wq0) {
#pragma unroll
                for (int kb = 0; kb < 2; kb++)
#pragma unroll
                    for (int r = 0; r < 4; r++) {
                        int key = k0 + kb * 16 + c;
                        int qq  = wq0 + g * 4 + r;
                        if (key > qq) s[kb][r] = -1.0e30f;
                    }
            }
            // ---- online softmax: row reductions across the 16 c-lanes ----
            float tm[4], pr0[4], pr1[4], rs[4], corr[4];
#pragma unroll
            for (int r = 0; r < 4; r++) tm[r] = fmaxf(s[0][r], s[1][r]);
#pragma unroll
            for (int off = 1; off <= 8; off <<= 1) {
#pragma unroll
                for (int r = 0; r < 4; r++)
                    tm[r] = fmaxf(tm[r], __shfl_xor(tm[r], off, 64));
            }
#pragma unroll
            for (int r = 0; r < 4; r++) {
                float mn = fmaxf(m_[r], tm[r]);
                corr[r] = __expf(m_[r] - mn);
                m_[r]   = mn;
                pr0[r]  = __expf(s[0][r] - mn);
                pr1[r]  = __expf(s[1][r] - mn);
                rs[r]   = pr0[r] + pr1[r];
            }
#pragma unroll
            for (int off = 1; off <= 8; off <<= 1) {
#pragma unroll
                for (int r = 0; r < 4; r++)
                    rs[r] += __shfl_xor(rs[r], off, 64);
            }
#pragma unroll
            for (int r = 0; r < 4; r++) l_[r] = l_[r] * corr[r] + rs[r];
#pragma unroll
            for (int dblk = 0; dblk < 4; dblk++)
#pragma unroll
                for (int r = 0; r < 4; r++) po[dblk][r] *= corr[r];
            // ---- P -> bf16, transpose through per-wave LDS to A layout ----
#pragma unroll
            for (int r = 0; r < 4; r++) {
                Ps[w][g * 4 + r][c]      = (short)bf16rne(pr0[r]);
                Ps[w][g * 4 + r][16 + c] = (short)bf16rne(pr1[r]);
            }
            short8 pa = *(const short8*)&Ps[w][c][g * 8];
            // ---- O += P V ----
#pragma unroll
            for (int dblk = 0; dblk < 4; dblk++) {
                short8 vf = *(const short8*)&Vt[dblk * 16 + c][g * 8];
                po[dblk] = __builtin_amdgcn_mfma_f32_16x16x32_bf16(pa, vf, po[dblk], 0, 0, 0);
            }
        }
        __syncthreads();
    }

    // ---- epilogue: O / l, store fp32 ----
#pragma unroll
    for (int r = 0; r < 4; r++) {
        float inv = 1.f / l_[r];
        float* yr = y + ((size_t)b * TSEQ + wq0 + g * 4 + r) * DM + h * HSZ + c;
#pragma unroll
        for (int dblk = 0; dblk < 4; dblk++)
            yr[dblk * 16] = po[dblk][r] * inv;
    }
}

// ---------------- SwiGLU elementwise ----------------
__global__ void silu_mul_kernel(float* __restrict__ g,
                                const float* __restrict__ u, int n) {
    int i = blockIdx.x * 256 + threadIdx.x;
    if (i < n) {
        float x = g[i];
        g[i] = (x / (1.f + expf(-x))) * u[i];
    }
}

extern "C" void kernel_launch(void* const* d_in, const int* in_sizes, int n_in,
                              void* d_out, int out_size, void* d_ws, size_t ws_size,
                              hipStream_t stream) {
    const int*   idx    = (const int*)d_in[0];
    const float* embed  = (const float*)d_in[1];
    const float* ln1_w  = (const float*)d_in[2];
    const float* q_w    = (const float*)d_in[3];
    const float* k_w    = (const float*)d_in[4];
    const float* v_w    = (const float*)d_in[5];
    const float* o_w    = (const float*)d_in[6];
    const float* ln2_w  = (const float*)d_in[7];
    const float* gate_w = (const float*)d_in[8];
    const float* up_w   = (const float*)d_in[9];
    const float* down_w = (const float*)d_in[10];
    const float* norm_w = (const float*)d_in[11];
    float* out = (float*)d_out;

    float* x  = (float*)d_ws;                 // NTOK*DM
    float* h  = x  + (size_t)NTOK * DM;       // NTOK*DM
    float* qb = h  + (size_t)NTOK * DM;       // NTOK*DM
    float* kb = qb + (size_t)NTOK * DM;       // NTOK*DKV
    float* vb = kb + (size_t)NTOK * DKV;      // NTOK*DKV
    float* yb = vb + (size_t)NTOK * DKV;      // NTOK*DM
    // MLP buffers alias the attention buffers (disjoint in time):
    float* gb = qb;                           // NTOK*IDIM
    float* ub = qb + (size_t)NTOK * IDIM;     // NTOK*IDIM

    dim3 blk(256);
    embed_kernel<<<NTOK, blk, 0, stream>>>(idx, embed, x);
    for (int l = 0; l < NLAY; l++) {
        rmsnorm_kernel<<<NTOK, blk, 0, stream>>>(x, ln1_w + (size_t)l * DM, h);
        // fused QKV: ranges {q:768 (6 blk), k:192 (2 blk), v:192 (2 blk)}
        gemm64_kernel<false><<<dim3(10, NTOK/64), blk, 0, stream>>>(
            h, q_w + (size_t)l*DM*DM, k_w + (size_t)l*DM*DKV, v_w + (size_t)l*DM*DKV,
            qb, kb, vb, NTOK, DM, DM, DKV, DKV, 6, 2);
        rope_kernel<<<(NTOK*NH*32   + 255)/256, blk, 0, stream>>>(qb, NH,   NTOK*NH*32);
        rope_kernel<<<(NTOK*NKVH*32 + 255)/256, blk, 0, stream>>>(kb, NKVH, NTOK*NKVH*32);
        attn_kernel<<<2 * NH * (TSEQ/64), blk, 0, stream>>>(qb, kb, vb, yb);
        gemm64_kernel<true><<<dim3(6, NTOK/64), blk, 0, stream>>>(
            yb, o_w + (size_t)l*DM*DM, nullptr, nullptr,
            x, nullptr, nullptr, NTOK, DM, DM, 0, 0, 6, 0);
        rmsnorm_kernel<<<NTOK, blk, 0, stream>>>(x, ln2_w + (size_t)l * DM, h);
        // fused gate|up: ranges {gate:2048 (16 blk), up:2048 (16 blk)}
        gemm64_kernel<false><<<dim3(32, NTOK/64), blk, 0, stream>>>(
            h, gate_w + (size_t)l*DM*IDIM, up_w + (size_t)l*DM*IDIM, nullptr,
            gb, ub, nullptr, NTOK, DM, IDIM, IDIM, 0, 16, 16);
        silu_mul_kernel<<<(NTOK*IDIM + 255)/256, blk, 0, stream>>>(gb, ub, NTOK*IDIM);
        gemm64_kernel<true><<<dim3(6, NTOK/64), blk, 0, stream>>>(
            gb, down_w + (size_t)l*IDIM*DM, nullptr, nullptr,
            x, nullptr, nullptr, NTOK, IDIM, DM, 0, 0, 6, 0);
    }
    rmsnorm_kernel<<<NTOK, blk, 0, stream>>>(x, norm_w, h);
    gemm_head_kernel<<<dim3((VOC+127)/128, NTOK/128), blk, 0, stream>>>(h, embed, out, NTOK, VOC, DM);
}

// Round 3
// 4248.161 us; speedup vs baseline: 6.9268x; 2.4129x over previous
//
#include <hip/hip_runtime.h>

// Llama-style forward: B=2,T=1024, D=768, H=12,HS=64, NKV=3 (GQA rep 4),
// L=12, I=2048, V=50257. idx int32, output fp32 logits (B,T,V).
// Fast path (needs ~506MB workspace): weights/embed pre-split to bf16 hi/lo
// [n][k] panels once per forward; GEMMs are double-buffered global_load_lds
// MFMA kernels (split-bf16 3-term: a*b ~= ah*bh + ah*bl + al*bh).
// Fallback path = previous verified kernels.

#define NTOK 2048      // B*T
#define DM   768
#define DKV  192       // NKV*HS
#define TSEQ 1024
#define NH   12
#define HSZ  64
#define NKVH 3
#define IDIM 2048
#define VOC  50257
#define NLAY 12

// per-layer packed-weight element offsets ([n][k] panels, hi & lo separate)
#define OFF_Q 0L
#define OFF_K 589824L
#define OFF_V 737280L
#define OFF_O 884736L
#define OFF_G 1474560L
#define OFF_U 3047424L
#define OFF_D 4620288L
#define WPL   6193152L

typedef __attribute__((ext_vector_type(8))) short short8;   // 8 bf16 (4 VGPR)
typedef __attribute__((ext_vector_type(4))) float f32x4;    // MFMA acc

#define GLD16(dst, src) __builtin_amdgcn_global_load_lds( \
    (const __attribute__((address_space(1))) void*)(src), \
    (__attribute__((address_space(3))) void*)(dst), 16, 0, 0)

// bf16 round-to-nearest-even
__device__ __forceinline__ unsigned short bf16rne(float x) {
    unsigned u = __float_as_uint(x);
    unsigned r = u + 0x7FFFu + ((u >> 16) & 1u);
    return (unsigned short)(r >> 16);
}
// truncation split: hi = trunc16(v), lo = trunc16(v - hi)
__device__ __forceinline__ void split_hl(float v, unsigned short& hi, unsigned short& lo) {
    unsigned u = __float_as_uint(v);
    hi = (unsigned short)(u >> 16);
    float l = v - __uint_as_float(u & 0xFFFF0000u);
    lo = (unsigned short)(__float_as_uint(l) >> 16);
}
// pack the high 16 bits (bf16 truncation) of two fp32 into one u32
__device__ __forceinline__ unsigned pack_hi(unsigned e0, unsigned e1) {
    return __builtin_amdgcn_perm(e1, e0, 0x07060302u);
}

// ---------------- embedding gather ----------------
__global__ void embed_kernel(const int* __restrict__ idx,
                             const float* __restrict__ embed,
                             float* __restrict__ x) {
    int tok = blockIdx.x;
    int row = idx[tok];
    for (int d = threadIdx.x; d < DM; d += 256)
        x[(size_t)tok * DM + d] = embed[(size_t)row * DM + d];
}

// ---------------- RMSNorm (SPLIT: emit bf16 hi/lo; else fp32) ----------------
template<bool SPLIT>
__global__ void rmsnorm_kernel(const float* __restrict__ x,
                               const float* __restrict__ w,
                               float* __restrict__ o,
                               unsigned short* __restrict__ ohi,
                               unsigned short* __restrict__ olo) {
    int tok = blockIdx.x;
    const float* xr = x + (size_t)tok * DM;
    float ss = 0.f;
    for (int d = threadIdx.x; d < DM; d += 256) { float v = xr[d]; ss += v * v; }
    __shared__ float red[256];
    red[threadIdx.x] = ss;
    __syncthreads();
    for (int s = 128; s > 0; s >>= 1) {
        if (threadIdx.x < s) red[threadIdx.x] += red[threadIdx.x + s];
        __syncthreads();
    }
    float rs = rsqrtf(red[0] / (float)DM + 1e-6f);
    for (int d = threadIdx.x; d < DM; d += 256) {
        float v = xr[d] * rs * w[d];
        if (SPLIT) {
            unsigned short hi, lo; split_hl(v, hi, lo);
            ohi[(size_t)tok * DM + d] = hi;
            olo[(size_t)tok * DM + d] = lo;
        } else {
            o[(size_t)tok * DM + d] = v;
        }
    }
}

// ---------------- embed -> bf16 hi/lo (elementwise) ----------------
__global__ void split_embed_kernel(const float* __restrict__ E,
                                   unsigned short* __restrict__ Eh,
                                   unsigned short* __restrict__ El, int n4) {
    for (int i = blockIdx.x * 256 + threadIdx.x; i < n4; i += gridDim.x * 256) {
        float4 v = ((const float4*)E)[i];
        ushort4 h, l;
        split_hl(v.x, h.x, l.x); split_hl(v.y, h.y, l.y);
        split_hl(v.z, h.z, l.z); split_hl(v.w, h.w, l.w);
        *(ushort4*)&Eh[(size_t)i * 4] = h;
        *(ushort4*)&El[(size_t)i * 4] = l;
    }
}

// ---------------- W[K,N] (per-layer) -> hi/lo bf16 [N][K] panels ----------------
__global__ void wsplit_t_kernel(const float* __restrict__ W,
                                unsigned short* __restrict__ Oh,
                                unsigned short* __restrict__ Ol,
                                int K, int N, long wstride, long ostride) {
    __shared__ float tile[32][33];
    const int t = threadIdx.x;
    int n0 = blockIdx.x * 32, k0 = blockIdx.y * 32, l = blockIdx.z;
    const float* Wz = W + (size_t)l * wstride;
    unsigned short* Hh = Oh + (size_t)l * ostride;
    unsigned short* Hl = Ol + (size_t)l * ostride;
    int tx = t & 31, ty = t >> 5;
#pragma unroll
    for (int p = 0; p < 4; p++)
        tile[p * 8 + ty][tx] = Wz[(size_t)(k0 + p * 8 + ty) * N + n0 + tx];
    __syncthreads();
#pragma unroll
    for (int p = 0; p < 4; p++) {
        int n = n0 + p * 8 + ty;
        float v = tile[tx][p * 8 + ty];
        unsigned short hi, lo; split_hl(v, hi, lo);
        Hh[(size_t)n * K + k0 + tx] = hi;
        Hl[(size_t)n * K + k0 + tx] = lo;
    }
}

// ============ layer GEMM: BM=64, BN=128, BK=32, double-buffered ============
// A hi/lo bf16 [M,K]; B hi/lo bf16 [n][k] panels; C fp32 (+RES). 3 ranges.
// LDS linear (global_load_lds); 16B-chunk XOR swizzle via per-lane source addr.
template<bool RES>
__global__ void gemm_bf_kernel(const unsigned short* __restrict__ Ahi,
                               const unsigned short* __restrict__ Alo,
                               const unsigned short* __restrict__ Whi,
                               const unsigned short* __restrict__ Wlo,
                               long off0, long off1, long off2,
                               float* __restrict__ C0, float* __restrict__ C1,
                               float* __restrict__ C2,
                               int K, int N0, int N1, int N2, int nb0, int nb1) {
    __shared__ unsigned short lds[2][12288];   // AH 0 | AL 2048 | BH 4096 | BL 8192

    const int t = threadIdx.x, lane = t & 63, w = t >> 6;
    const int nb = blockIdx.x;
    const unsigned short *Bh, *Bl; float* C; int N; int nloc;
    if (nb < nb0)            { Bh = Whi + off0; Bl = Wlo + off0; C = C0; N = N0; nloc = nb; }
    else if (nb < nb0 + nb1) { Bh = Whi + off1; Bl = Wlo + off1; C = C1; N = N1; nloc = nb - nb0; }
    else                     { Bh = Whi + off2; Bl = Wlo + off2; C = C2; N = N2; nloc = nb - nb0 - nb1; }
    const int n0 = nloc * 128;
    const int m0 = blockIdx.y * 64;
    const int wr = w >> 1, wc = w & 1;

    // staging lane map: row = r0 + (lane>>2), chunk = lane&3; source chunk XOR'd
    const int srow  = lane >> 2;
    const int soct8 = ((lane & 3) ^ ((srow + (lane >> 4)) & 3)) * 8;  // ushorts
    const unsigned short* aSh = Ahi + (size_t)(m0 + w * 16 + srow) * K + soct8;
    const unsigned short* aSl = Alo + (size_t)(m0 + w * 16 + srow) * K + soct8;
    int nr0 = n0 + w * 32 + srow;      if (nr0 > N - 1) nr0 = N - 1;
    int nr1 = n0 + w * 32 + 16 + srow; if (nr1 > N - 1) nr1 = N - 1;
    const unsigned short* bSh0 = Bh + (size_t)nr0 * K + soct8;
    const unsigned short* bSh1 = Bh + (size_t)nr1 * K + soct8;
    const unsigned short* bSl0 = Bl + (size_t)nr0 * K + soct8;
    const unsigned short* bSl1 = Bl + (size_t)nr1 * K + soct8;

    // fragment read: row = base + lr, source octet g recovered via same XOR
    const int lr = lane & 15, g = lane >> 4;
    const int fo = (g ^ ((lr + (lr >> 2)) & 3)) * 8;                  // ushorts

#define STAGE_L(cb, kk) { unsigned short* bb = &lds[cb][0];            \
    GLD16(bb +        (w * 16) * 32,      aSh  + (kk));                \
    GLD16(bb + 2048 + (w * 16) * 32,      aSl  + (kk));                \
    GLD16(bb + 4096 + (w * 32) * 32,      bSh0 + (kk));                \
    GLD16(bb + 4096 + (w * 32 + 16) * 32, bSh1 + (kk));                \
    GLD16(bb + 8192 + (w * 32) * 32,      bSl0 + (kk));                \
    GLD16(bb + 8192 + (w * 32 + 16) * 32, bSl1 + (kk)); }

    f32x4 acc[2][4] = {};
    const int nt = K / 32;
    STAGE_L(0, 0);
    asm volatile("s_waitcnt vmcnt(0)" ::: "memory");
    __syncthreads();
    int cur = 0;
    for (int tt = 0; tt < nt; tt++) {
        if (tt + 1 < nt) STAGE_L(cur ^ 1, (tt + 1) * 32);
        const unsigned short* bb = &lds[cur][0];
        short8 ah[2], al[2], bh[4], bl[4];
#pragma unroll
        for (int mi = 0; mi < 2; mi++) {
            int r = wr * 32 + mi * 16 + lr;
            ah[mi] = *(const short8*)(bb + r * 32 + fo);
            al[mi] = *(const short8*)(bb + 2048 + r * 32 + fo);
        }
#pragma unroll
        for (int ni = 0; ni < 4; ni++) {
            int r = wc * 64 + ni * 16 + lr;
            bh[ni] = *(const short8*)(bb + 4096 + r * 32 + fo);
            bl[ni] = *(const short8*)(bb + 8192 + r * 32 + fo);
        }
#pragma unroll
        for (int mi = 0; mi < 2; mi++)
#pragma unroll
            for (int ni = 0; ni < 4; ni++) {
                f32x4 c = acc[mi][ni];
                c = __builtin_amdgcn_mfma_f32_16x16x32_bf16(ah[mi], bh[ni], c, 0, 0, 0);
                c = __builtin_amdgcn_mfma_f32_16x16x32_bf16(ah[mi], bl[ni], c, 0, 0, 0);
                c = __builtin_amdgcn_mfma_f32_16x16x32_bf16(al[mi], bh[ni], c, 0, 0, 0);
                acc[mi][ni] = c;
            }
        asm volatile("s_waitcnt vmcnt(0)" ::: "memory");
        __syncthreads();
        cur ^= 1;
    }
#undef STAGE_L

    const int cr = (lane >> 4) * 4, cc = lane & 15;
#pragma unroll
    for (int mi = 0; mi < 2; mi++) {
#pragma unroll
        for (int ni = 0; ni < 4; ni++) {
            int gr = m0 + wr * 32 + mi * 16 + cr;
            int gc = n0 + wc * 64 + ni * 16 + cc;
            if (gc < N) {
#pragma unroll
                for (int r = 0; r < 4; r++) {
                    size_t o = (size_t)(gr + r) * N + gc;
                    float v = acc[mi][ni][r];
                    if (RES) v += C[o];
                    C[o] = v;
                }
            }
        }
    }
}

// ============ head GEMM: BM=128, BN=128, BK=32, double-buffered ============
// A = h hi/lo bf16 [M,K]; B = embed hi/lo bf16 [V][K]; XCD-swizzled 1D grid.
__global__ void gemm_head_bf_kernel(const unsigned short* __restrict__ Ahi,
                                    const unsigned short* __restrict__ Alo,
                                    const unsigned short* __restrict__ Bhg,
                                    const unsigned short* __restrict__ Blg,
                                    float* __restrict__ C, int M, int N, int K) {
    __shared__ unsigned short lds[2][16384];   // AH 0 | AL 4096 | BH 8192 | BL 12288

    const int t = threadIdx.x, lane = t & 63, w = t >> 6;
    // bijective XCD swizzle (6288 = 8*786), m-fastest for B-panel L2 reuse
    int wg = blockIdx.x;
    int sz = (wg & 7) * 786 + (wg >> 3);
    const int m0 = (sz & 15) * 128;
    const int n0 = (sz >> 4) * 128;
    const int wr = w >> 1, wc = w & 1;

    const int srow  = lane >> 2;
    const int soct8 = ((lane & 3) ^ ((srow + (lane >> 4)) & 3)) * 8;
    const unsigned short* aS0 = Ahi + (size_t)(m0 + w * 32 + srow) * K + soct8;
    const unsigned short* aS1 = Ahi + (size_t)(m0 + w * 32 + 16 + srow) * K + soct8;
    const unsigned short* aL0 = Alo + (size_t)(m0 + w * 32 + srow) * K + soct8;
    const unsigned short* aL1 = Alo + (size_t)(m0 + w * 32 + 16 + srow) * K + soct8;
    int nr0 = n0 + w * 32 + srow;      if (nr0 > N - 1) nr0 = N - 1;
    int nr1 = n0 + w * 32 + 16 + srow; if (nr1 > N - 1) nr1 = N - 1;
    const unsigned short* bS0 = Bhg + (size_t)nr0 * K + soct8;
    const unsigned short* bS1 = Bhg + (size_t)nr1 * K + soct8;
    const unsigned short* bL0 = Blg + (size_t)nr0 * K + soct8;
    const unsigned short* bL1 = Blg + (size_t)nr1 * K + soct8;

    const int lr = lane & 15, g = lane >> 4;
    const int fo = (g ^ ((lr + (lr >> 2)) & 3)) * 8;

#define STAGE_H(cb, kk) { unsigned short* bb = &lds[cb][0];              \
    GLD16(bb +         (w * 32) * 32,      aS0 + (kk));                  \
    GLD16(bb +         (w * 32 + 16) * 32, aS1 + (kk));                  \
    GLD16(bb +  4096 + (w * 32) * 32,      aL0 + (kk));                  \
    GLD16(bb +  4096 + (w * 32 + 16) * 32, aL1 + (kk));                  \
    GLD16(bb +  8192 + (w * 32) * 32,      bS0 + (kk));                  \
    GLD16(bb +  8192 + (w * 32 + 16) * 32, bS1 + (kk));                  \
    GLD16(bb + 12288 + (w * 32) * 32,      bL0 + (kk));                  \
    GLD16(bb + 12288 + (w * 32 + 16) * 32, bL1 + (kk)); }

    f32x4 acc[4][4] = {};
    const int nt = K / 32;
    STAGE_H(0, 0);
    asm volatile("s_waitcnt vmcnt(0)" ::: "memory");
    __syncthreads();
    int cur = 0;
    for (int tt = 0; tt < nt; tt++) {
        if (tt + 1 < nt) STAGE_H(cur ^ 1, (tt + 1) * 32);
        const unsigned short* bb = &lds[cur][0];
        short8 ah[4], al[4], bh[4], bl[4];
#pragma unroll
        for (int mi = 0; mi < 4; mi++) {
            int r = wr * 64 + mi * 16 + lr;
            ah[mi] = *(const short8*)(bb + r * 32 + fo);
            al[mi] = *(const short8*)(bb + 4096 + r * 32 + fo);
        }
#pragma unroll
        for (int ni = 0; ni < 4; ni++) {
            int r = wc * 64 + ni * 16 + lr;
            bh[ni] = *(const short8*)(bb + 8192 + r * 32 + fo);
            bl[ni] = *(const short8*)(bb + 12288 + r * 32 + fo);
        }
#pragma unroll
        for (int mi = 0; mi < 4; mi++)
#pragma unroll
            for (int ni = 0; ni < 4; ni++) {
                f32x4 c = acc[mi][ni];
                c = __builtin_amdgcn_mfma_f32_16x16x32_bf16(ah[mi], bh[ni], c, 0, 0, 0);
                c = __builtin_amdgcn_mfma_f32_16x16x32_bf16(ah[mi], bl[ni], c, 0, 0, 0);
                c = __builtin_amdgcn_mfma_f32_16x16x32_bf16(al[mi], bh[ni], c, 0, 0, 0);
                acc[mi][ni] = c;
            }
        asm volatile("s_waitcnt vmcnt(0)" ::: "memory");
        __syncthreads();
        cur ^= 1;
    }
#undef STAGE_H

    const int cr = (lane >> 4) * 4, cc = lane & 15;
#pragma unroll
    for (int mi = 0; mi < 4; mi++) {
#pragma unroll
        for (int ni = 0; ni < 4; ni++) {
            int gr = m0 + wr * 64 + mi * 16 + cr;
            int gc = n0 + wc * 64 + ni * 16 + cc;
            if (gc < N) {
#pragma unroll
                for (int r = 0; r < 4; r++)
                    C[(size_t)(gr + r) * N + gc] = acc[mi][ni][r];
            }
        }
    }
}

// ---------------- RoPE (rotate-half, half=32, full head dim 64) ----------------
__global__ void rope_kernel(float* __restrict__ p, int nheads, int total) {
    int gid = blockIdx.x * 256 + threadIdx.x;
    if (gid >= total) return;
    int j    = gid & 31;
    int rest = gid >> 5;
    int h    = rest % nheads;
    int tok  = rest / nheads;
    int pos  = tok & (TSEQ - 1);
    float freq = powf(10000.f, (float)j * (1.f / 32.f));
    float ang  = (float)pos / freq;
    float s = sinf(ang), c = cosf(ang);
    float* row = p + (size_t)tok * (nheads * HSZ) + h * HSZ;
    float a = row[j], b = row[j + 32];
    row[j]      = a * c - b * s;
    row[j + 32] = b * c + a * s;
}

// ---------------- flash attention: MFMA QK^T + PV, online softmax ----------------
// SPLIT: epilogue emits y as bf16 hi/lo (for the o-proj GEMM); else fp32.
template<bool SPLIT>
__global__ void attn_kernel(const float* __restrict__ q,
                            const float* __restrict__ k,
                            const float* __restrict__ v,
                            float* __restrict__ y,
                            unsigned short* __restrict__ yh,
                            unsigned short* __restrict__ yl) {
    __shared__ short Ks[32][72];
    __shared__ short Vt[64][40];
    __shared__ short Ps[4][16][40];

    const int t = threadIdx.x, lane = t & 63, w = t >> 6;
    const int qt = blockIdx.x & 15;
    const int h  = (blockIdx.x >> 4) % NH;
    const int b  = blockIdx.x / (16 * NH);
    const int q0 = qt * 64;
    const int wq0 = q0 + w * 16;
    const int kvh = h % NKVH;
    const int g = lane >> 4, c = lane & 15;

    short8 qf[2];
    {
        const float* qr = q + ((size_t)b * TSEQ + wq0 + c) * DM + h * HSZ + g * 8;
#pragma unroll
        for (int dh = 0; dh < 2; dh++) {
            float4 a0 = *(const float4*)(qr + dh * 32);
            float4 a1 = *(const float4*)(qr + dh * 32 + 4);
            short8 s8;
            s8[0] = (short)bf16rne(a0.x * 0.125f);
            s8[1] = (short)bf16rne(a0.y * 0.125f);
            s8[2] = (short)bf16rne(a0.z * 0.125f);
            s8[3] = (short)bf16rne(a0.w * 0.125f);
            s8[4] = (short)bf16rne(a1.x * 0.125f);
            s8[5] = (short)bf16rne(a1.y * 0.125f);
            s8[6] = (short)bf16rne(a1.z * 0.125f);
            s8[7] = (short)bf16rne(a1.w * 0.125f);
            qf[dh] = s8;
        }
    }

    f32x4 po[4] = {};
    float m_[4] = {-3.0e38f, -3.0e38f, -3.0e38f, -3.0e38f};
    float l_[4] = {};

    const int kmax = q0 + 63;
    for (int k0 = 0; k0 <= kmax; k0 += 32) {
        {
            int kr = t >> 3, kq = t & 7;
            const float* kp = k + ((size_t)b * TSEQ + k0 + kr) * DKV + kvh * HSZ + kq * 8;
            float4 b0 = *(const float4*)kp;
            float4 b1 = *(const float4*)(kp + 4);
            short8 s8;
            s8[0] = (short)bf16rne(b0.x); s8[1] = (short)bf16rne(b0.y);
            s8[2] = (short)bf16rne(b0.z); s8[3] = (short)bf16rne(b0.w);
            s8[4] = (short)bf16rne(b1.x); s8[5] = (short)bf16rne(b1.y);
            s8[6] = (short)bf16rne(b1.z); s8[7] = (short)bf16rne(b1.w);
            *(short8*)&Ks[kr][kq * 8] = s8;

            int vk = t & 31, dq = t >> 5;
            const float* vp = v + ((size_t)b * TSEQ + k0 + vk) * DKV + kvh * HSZ + dq * 8;
            float4 c0 = *(const float4*)vp;
            float4 c1 = *(const float4*)(vp + 4);
            Vt[dq * 8 + 0][vk] = (short)bf16rne(c0.x);
            Vt[dq * 8 + 1][vk] = (short)bf16rne(c0.y);
            Vt[dq * 8 + 2][vk] = (short)bf16rne(c0.z);
            Vt[dq * 8 + 3][vk] = (short)bf16rne(c0.w);
            Vt[dq * 8 + 4][vk] = (short)bf16rne(c1.x);
            Vt[dq * 8 + 5][vk] = (short)bf16rne(c1.y);
            Vt[dq * 8 + 6][vk] = (short)bf16rne(c1.z);
            Vt[dq * 8 + 7][vk] = (short)bf16rne(c1.w);
        }
        __syncthreads();

        if (k0 <= wq0 + 15) {
            f32x4 s[2];
#pragma unroll
            for (int kb = 0; kb < 2; kb++) {
                short8 kf0 = *(const short8*)&Ks[kb * 16 + c][g * 8];
                short8 kf1 = *(const short8*)&Ks[kb * 16 + c][32 + g * 8];
                f32x4 a = {};
                a = __builtin_amdgcn_mfma_f32_16x16x32_bf16(qf[0], kf0, a, 0, 0, 0);
                a = __builtin_amdgcn_mfma_f32_16x16x32_bf16(qf[1], kf1, a, 0, 0, 0);
                s[kb] = a;
            }
            if (k0 + 31 > wq0) {
#pragma unroll
                for (int kb = 0; kb < 2; kb++)
#pragma unroll
                    for (int r = 0; r < 4; r++) {
                        int key = k0 + kb * 16 + c;
                        int qq  = wq0 + g * 4 + r;
                        if (key > qq) s[kb][r] = -1.0e30f;
                    }
            }
            float tm[4], pr0[4], pr1[4], rs[4], corr[4];
#pragma unroll
            for (int r = 0; r < 4; r++) tm[r] = fmaxf(s[0][r], s[1][r]);
#pragma unroll
            for (int off = 1; off <= 8; off <<= 1) {
#pragma unroll
                for (int r = 0; r < 4; r++)
                    tm[r] = fmaxf(tm[r], __shfl_xor(tm[r], off, 64));
            }
#pragma unroll
            for (int r = 0; r < 4; r++) {
                float mn = fmaxf(m_[r], tm[r]);
                corr[r] = __expf(m_[r] - mn);
                m_[r]   = mn;
                pr0[r]  = __expf(s[0][r] - mn);
                pr1[r]  = __expf(s[1][r] - mn);
                rs[r]   = pr0[r] + pr1[r];
            }
#pragma unroll
            for (int off = 1; off <= 8; off <<= 1) {
#pragma unroll
                for (int r = 0; r < 4; r++)
                    rs[r] += __shfl_xor(rs[r], off, 64);
            }
#pragma unroll
            for (int r = 0; r < 4; r++) l_[r] = l_[r] * corr[r] + rs[r];
#pragma unroll
            for (int dblk = 0; dblk < 4; dblk++)
#pragma unroll
                for (int r = 0; r < 4; r++) po[dblk][r] *= corr[r];
#pragma unroll
            for (int r = 0; r < 4; r++) {
                Ps[w][g * 4 + r][c]      = (short)bf16rne(pr0[r]);
                Ps[w][g * 4 + r][16 + c] = (short)bf16rne(pr1[r]);
            }
            short8 pa = *(const short8*)&Ps[w][c][g * 8];
#pragma unroll
            for (int dblk = 0; dblk < 4; dblk++) {
                short8 vf = *(const short8*)&Vt[dblk * 16 + c][g * 8];
                po[dblk] = __builtin_amdgcn_mfma_f32_16x16x32_bf16(pa, vf, po[dblk], 0, 0, 0);
            }
        }
        __syncthreads();
    }

#pragma unroll
    for (int r = 0; r < 4; r++) {
        float inv = 1.f / l_[r];
        size_t base = ((size_t)b * TSEQ + wq0 + g * 4 + r) * DM + h * HSZ + c;
#pragma unroll
        for (int dblk = 0; dblk < 4; dblk++) {
            float val = po[dblk][r] * inv;
            if (SPLIT) {
                unsigned short hi, lo; split_hl(val, hi, lo);
                yh[base + dblk * 16] = hi;
                yl[base + dblk * 16] = lo;
            } else {
                y[base + dblk * 16] = val;
            }
        }
    }
}

// ---------------- SwiGLU elementwise (SPLIT: emit bf16 hi/lo) ----------------
template<bool SPLIT>
__global__ void silu_mul_kernel(float* __restrict__ g,
                                const float* __restrict__ u,
                                unsigned short* __restrict__ gh,
                                unsigned short* __restrict__ gl, int n) {
    int i = blockIdx.x * 256 + threadIdx.x;
    if (i < n) {
        float x = g[i];
        float val = (x / (1.f + expf(-x))) * u[i];
        if (SPLIT) {
            unsigned short hi, lo; split_hl(val, hi, lo);
            gh[i] = hi; gl[i] = lo;
        } else {
            g[i] = val;
        }
    }
}

// ================= FALLBACK (round-2 verified) GEMMs =================
__global__ void gemm_head_f32_kernel(const float* __restrict__ A,
                                     const float* __restrict__ B,
                                     float* __restrict__ C, int M, int N, int K) {
    __shared__ short Ah[128][40];
    __shared__ short Al[128][40];
    __shared__ short Bh[128][40];
    __shared__ short Bl[128][40];
    const int t    = threadIdx.x;
    const int m0   = blockIdx.y * 128;
    const int n0   = blockIdx.x * 128;
    const int lane = t & 63, w = t >> 6;
    const int wr   = w >> 1, wc = w & 1;
    const int lr   = lane & 15;
    const int lk   = (lane >> 4) * 8;
    f32x4 acc[4][4] = {};
    for (int k0 = 0; k0 < K; k0 += 32) {
#pragma unroll
        for (int i = 0; i < 4; i++) {
            int gg = t + 256 * i;
            int row = gg >> 3, kq = gg & 7;
            float4 av = *(const float4*)&A[(size_t)(m0 + row) * K + k0 + kq * 4];
            unsigned b0 = __float_as_uint(av.x), b1 = __float_as_uint(av.y);
            unsigned b2 = __float_as_uint(av.z), b3 = __float_as_uint(av.w);
            float l0 = av.x - __uint_as_float(b0 & 0xFFFF0000u);
            float l1 = av.y - __uint_as_float(b1 & 0xFFFF0000u);
            float l2 = av.z - __uint_as_float(b2 & 0xFFFF0000u);
            float l3 = av.w - __uint_as_float(b3 & 0xFFFF0000u);
            *(uint2*)&Ah[row][kq * 4] = make_uint2(pack_hi(b0, b1), pack_hi(b2, b3));
            *(uint2*)&Al[row][kq * 4] =
                make_uint2(pack_hi(__float_as_uint(l0), __float_as_uint(l1)),
                           pack_hi(__float_as_uint(l2), __float_as_uint(l3)));
        }
#pragma unroll
        for (int i = 0; i < 4; i++) {
            int gg = t + 256 * i;
            int row = gg >> 3, kq = gg & 7;
            int n = n0 + row;
            float4 bv = make_float4(0.f, 0.f, 0.f, 0.f);
            if (n < N) bv = *(const float4*)&B[(size_t)n * K + k0 + kq * 4];
            unsigned b0 = __float_as_uint(bv.x), b1 = __float_as_uint(bv.y);
            unsigned b2 = __float_as_uint(bv.z), b3 = __float_as_uint(bv.w);
            float l0 = bv.x - __uint_as_float(b0 & 0xFFFF0000u);
            float l1 = bv.y - __uint_as_float(b1 & 0xFFFF0000u);
            float l2 = bv.z - __uint_as_float(b2 & 0xFFFF0000u);
            float l3 = bv.w - __uint_as_float(b3 & 0xFFFF0000u);
            *(uint2*)&Bh[row][kq * 4] = make_uint2(pack_hi(b0, b1), pack_hi(b2, b3));
            *(uint2*)&Bl[row][kq * 4] =
                make_uint2(pack_hi(__float_as_uint(l0), __float_as_uint(l1)),
                           pack_hi(__float_as_uint(l2), __float_as_uint(l3)));
        }
        __syncthreads();
        short8 ah[4], al[4], bh[4], bl[4];
#pragma unroll
        for (int mi = 0; mi < 4; mi++) {
            int r = wr * 64 + mi * 16 + lr;
            ah[mi] = *(const short8*)&Ah[r][lk];
            al[mi] = *(const short8*)&Al[r][lk];
        }
#pragma unroll
        for (int ni = 0; ni < 4; ni++) {
            int r = wc * 64 + ni * 16 + lr;
            bh[ni] = *(const short8*)&Bh[r][lk];
            bl[ni] = *(const short8*)&Bl[r][lk];
        }
#pragma unroll
        for (int mi = 0; mi < 4; mi++)
#pragma unroll
            for (int ni = 0; ni < 4; ni++) {
                f32x4 c = acc[mi][ni];
                c = __builtin_amdgcn_mfma_f32_16x16x32_bf16(ah[mi], bh[ni], c, 0, 0, 0);
                c = __builtin_amdgcn_mfma_f32_16x16x32_bf16(ah[mi], bl[ni], c, 0, 0, 0);
                c = __builtin_amdgcn_mfma_f32_16x16x32_bf16(al[mi], bh[ni], c, 0, 0, 0);
                acc[mi][ni] = c;
            }
        __syncthreads();
    }
    const int cr = (lane >> 4) * 4, cc = lane & 15;
#pragma unroll
    for (int mi = 0; mi < 4; mi++) {
#pragma unroll
        for (int ni = 0; ni < 4; ni++) {
            int gr = m0 + wr * 64 + mi * 16 + cr;
            int gc = n0 + wc * 64 + ni * 16 + cc;
            if (gc < N) {
#pragma unroll
                for (int r = 0; r < 4; r++)
                    C[(size_t)(gr + r) * N + gc] = acc[mi][ni][r];
            }
        }
    }
}

template<bool RES>
__global__ void gemm64_f32_kernel(const float* __restrict__ A,
                                  const float* __restrict__ B0, const float* __restrict__ B1,
                                  const float* __restrict__ B2,
                                  float* __restrict__ C0, float* __restrict__ C1,
                                  float* __restrict__ C2,
                                  int M, int K, int N0, int N1, int N2,
                                  int nb0, int nb1) {
    __shared__ short Ah[64][40];
    __shared__ short Al[64][40];
    __shared__ short Bh[128][40];
    __shared__ short Bl[128][40];
    const int t  = threadIdx.x;
    const int nb = blockIdx.x;
    const float* B; float* C; int N; int nloc;
    if (nb < nb0)            { B = B0; C = C0; N = N0; nloc = nb; }
    else if (nb < nb0 + nb1) { B = B1; C = C1; N = N1; nloc = nb - nb0; }
    else                     { B = B2; C = C2; N = N2; nloc = nb - nb0 - nb1; }
    const int n0 = nloc * 128;
    const int m0 = blockIdx.y * 64;
    const int lane = t & 63, w = t >> 6;
    const int wr   = w >> 1, wc = w & 1;
    const int lr   = lane & 15;
    const int lk   = (lane >> 4) * 8;
    f32x4 acc[2][4] = {};
    for (int k0 = 0; k0 < K; k0 += 32) {
#pragma unroll
        for (int i = 0; i < 2; i++) {
            int gg = t + 256 * i;
            int row = gg >> 3, kq = gg & 7;
            float4 av = *(const float4*)&A[(size_t)(m0 + row) * K + k0 + kq * 4];
            unsigned b0 = __float_as_uint(av.x), b1 = __float_as_uint(av.y);
            unsigned b2 = __float_as_uint(av.z), b3 = __float_as_uint(av.w);
            float l0 = av.x - __uint_as_float(b0 & 0xFFFF0000u);
            float l1 = av.y - __uint_as_float(b1 & 0xFFFF0000u);
            float l2 = av.z - __uint_as_float(b2 & 0xFFFF0000u);
            float l3 = av.w - __uint_as_float(b3 & 0xFFFF0000u);
            *(uint2*)&Ah[row][kq * 4] = make_uint2(pack_hi(b0, b1), pack_hi(b2, b3));
            *(uint2*)&Al[row][kq * 4] =
                make_uint2(pack_hi(__float_as_uint(l0), __float_as_uint(l1)),
                           pack_hi(__float_as_uint(l2), __float_as_uint(l3)));
        }
#pragma unroll
        for (int i = 0; i < 4; i++) {
            int gg = t + 256 * i;
            int kk = gg >> 5, nq = gg & 31;
            int n = n0 + nq * 4;
            float4 bv = (n < N) ? *(const float4*)&B[(size_t)(k0 + kk) * N + n]
                                : make_float4(0.f, 0.f, 0.f, 0.f);
            float el[4] = {bv.x, bv.y, bv.z, bv.w};
#pragma unroll
            for (int e = 0; e < 4; e++) {
                unsigned bu = __float_as_uint(el[e]);
                float lo = el[e] - __uint_as_float(bu & 0xFFFF0000u);
                Bh[nq * 4 + e][kk] = (short)(bu >> 16);
                Bl[nq * 4 + e][kk] = (short)(__float_as_uint(lo) >> 16);
            }
        }
        __syncthreads();
        short8 ah[2], al[2], bh[4], bl[4];
#pragma unroll
        for (int mi = 0; mi < 2; mi++) {
            int r = wr * 32 + mi * 16 + lr;
            ah[mi] = *(const short8*)&Ah[r][lk];
            al[mi] = *(const short8*)&Al[r][lk];
        }
#pragma unroll
        for (int ni = 0; ni < 4; ni++) {
            int r = wc * 64 + ni * 16 + lr;
            bh[ni] = *(const short8*)&Bh[r][lk];
            bl[ni] = *(const short8*)&Bl[r][lk];
        }
#pragma unroll
        for (int mi = 0; mi < 2; mi++)
#pragma unroll
            for (int ni = 0; ni < 4; ni++) {
                f32x4 c = acc[mi][ni];
                c = __builtin_amdgcn_mfma_f32_16x16x32_bf16(ah[mi], bh[ni], c, 0, 0, 0);
                c = __builtin_amdgcn_mfma_f32_16x16x32_bf16(ah[mi], bl[ni], c, 0, 0, 0);
                c = __builtin_amdgcn_mfma_f32_16x16x32_bf16(al[mi], bh[ni], c, 0, 0, 0);
                acc[mi][ni] = c;
            }
        __syncthreads();
    }
    const int cr = (lane >> 4) * 4, cc = lane & 15;
#pragma unroll
    for (int mi = 0; mi < 2; mi++) {
#pragma unroll
        for (int ni = 0; ni < 4; ni++) {
            int gr = m0 + wr * 32 + mi * 16 + cr;
            int gc = n0 + wc * 64 + ni * 16 + cc;
            if (gc < N) {
#pragma unroll
                for (int r = 0; r < 4; r++) {
                    size_t o = (size_t)(gr + r) * N + gc;
                    float v = acc[mi][ni][r];
                    if (RES) v += C[o];
                    C[o] = v;
                }
            }
        }
    }
}

extern "C" void kernel_launch(void* const* d_in, const int* in_sizes, int n_in,
                              void* d_out, int out_size, void* d_ws, size_t ws_size,
                              hipStream_t stream) {
    const int*   idx    = (const int*)d_in[0];
    const float* embed  = (const float*)d_in[1];
    const float* ln1_w  = (const float*)d_in[2];
    const float* q_w    = (const float*)d_in[3];
    const float* k_w    = (const float*)d_in[4];
    const float* v_w    = (const float*)d_in[5];
    const float* o_w    = (const float*)d_in[6];
    const float* ln2_w  = (const float*)d_in[7];
    const float* gate_w = (const float*)d_in[8];
    const float* up_w   = (const float*)d_in[9];
    const float* down_w = (const float*)d_in[10];
    const float* norm_w = (const float*)d_in[11];
    float* out = (float*)d_out;
    dim3 blk(256);

    const size_t NEED = 530304000ull;
    if (ws_size >= NEED) {
        // ---------- fast path layout ----------
        char* p = (char*)d_ws;
        float* x  = (float*)p;              p += (size_t)NTOK * DM * 4;
        float* qb = (float*)p;              p += (size_t)NTOK * DM * 4;
        float* kb = (float*)p;              p += (size_t)NTOK * DKV * 4;
        float* vb = (float*)p;              p += (size_t)NTOK * DKV * 4;
        float* gb = (float*)p;              p += (size_t)NTOK * IDIM * 4;
        float* ub = (float*)p;              p += (size_t)NTOK * IDIM * 4;
        unsigned short* hh = (unsigned short*)p; p += (size_t)NTOK * DM * 2;
        unsigned short* hl = (unsigned short*)p; p += (size_t)NTOK * DM * 2;
        unsigned short* yh = (unsigned short*)p; p += (size_t)NTOK * DM * 2;
        unsigned short* yl = (unsigned short*)p; p += (size_t)NTOK * DM * 2;
        unsigned short* gh = (unsigned short*)p; p += (size_t)NTOK * IDIM * 2;
        unsigned short* gl = (unsigned short*)p; p += (size_t)NTOK * IDIM * 2;
        unsigned short* eh = (unsigned short*)p; p += (size_t)VOC * DM * 2;
        unsigned short* el = (unsigned short*)p; p += (size_t)VOC * DM * 2;
        unsigned short* wh = (unsigned short*)p; p += (size_t)WPL * NLAY * 2;
        unsigned short* wl = (unsigned short*)p;

        // ---------- weight / embed prep ----------
        split_embed_kernel<<<2048, blk, 0, stream>>>(embed, eh, el, VOC * DM / 4);
        wsplit_t_kernel<<<dim3(24, 24, 12), blk, 0, stream>>>(q_w,    wh + OFF_Q, wl + OFF_Q, 768, 768,  589824L,  WPL);
        wsplit_t_kernel<<<dim3(6,  24, 12), blk, 0, stream>>>(k_w,    wh + OFF_K, wl + OFF_K, 768, 192,  147456L,  WPL);
        wsplit_t_kernel<<<dim3(6,  24, 12), blk, 0, stream>>>(v_w,    wh + OFF_V, wl + OFF_V, 768, 192,  147456L,  WPL);
        wsplit_t_kernel<<<dim3(24, 24, 12), blk, 0, stream>>>(o_w,    wh + OFF_O, wl + OFF_O, 768, 768,  589824L,  WPL);
        wsplit_t_kernel<<<dim3(64, 24, 12), blk, 0, stream>>>(gate_w, wh + OFF_G, wl + OFF_G, 768, 2048, 1572864L, WPL);
        wsplit_t_kernel<<<dim3(64, 24, 12), blk, 0, stream>>>(up_w,   wh + OFF_U, wl + OFF_U, 768, 2048, 1572864L, WPL);
        wsplit_t_kernel<<<dim3(24, 64, 12), blk, 0, stream>>>(down_w, wh + OFF_D, wl + OFF_D, 2048, 768, 1572864L, WPL);

        embed_kernel<<<NTOK, blk, 0, stream>>>(idx, embed, x);
        for (int l = 0; l < NLAY; l++) {
            long lw = (long)l * WPL;
            rmsnorm_kernel<true><<<NTOK, blk, 0, stream>>>(x, ln1_w + (size_t)l * DM, nullptr, hh, hl);
            gemm_bf_kernel<false><<<dim3(10, 32), blk, 0, stream>>>(
                hh, hl, wh, wl, lw + OFF_Q, lw + OFF_K, lw + OFF_V,
                qb, kb, vb, 768, DM, DKV, DKV, 6, 2);
            rope_kernel<<<(NTOK*NH*32   + 255)/256, blk, 0, stream>>>(qb, NH,   NTOK*NH*32);
            rope_kernel<<<(NTOK*NKVH*32 + 255)/256, blk, 0, stream>>>(kb, NKVH, NTOK*NKVH*32);
            attn_kernel<true><<<2 * NH * (TSEQ/64), blk, 0, stream>>>(qb, kb, vb, nullptr, yh, yl);
            gemm_bf_kernel<true><<<dim3(6, 32), blk, 0, stream>>>(
                yh, yl, wh, wl, lw + OFF_O, lw + OFF_O, lw + OFF_O,
                x, x, x, 768, DM, 0, 0, 6, 0);
            rmsnorm_kernel<true><<<NTOK, blk, 0, stream>>>(x, ln2_w + (size_t)l * DM, nullptr, hh, hl);
            gemm_bf_kernel<false><<<dim3(32, 32), blk, 0, stream>>>(
                hh, hl, wh, wl, lw + OFF_G, lw + OFF_U, lw + OFF_U,
                gb, ub, ub, 768, IDIM, IDIM, 0, 16, 16);
            silu_mul_kernel<true><<<(NTOK*IDIM + 255)/256, blk, 0, stream>>>(gb, ub, gh, gl, NTOK*IDIM);
            gemm_bf_kernel<true><<<dim3(6, 32), blk, 0, stream>>>(
                gh, gl, wh, wl, lw + OFF_D, lw + OFF_D, lw + OFF_D,
                x, x, x, 2048, DM, 0, 0, 6, 0);
        }
        rmsnorm_kernel<true><<<NTOK, blk, 0, stream>>>(x, norm_w, nullptr, hh, hl);
        gemm_head_bf_kernel<<<6288, blk, 0, stream>>>(hh, hl, eh, el, out, NTOK, VOC, DM);
    } else {
        // ---------- fallback: round-2 verified path ----------
        float* x  = (float*)d_ws;
        float* h  = x  + (size_t)NTOK * DM;
        float* qb = h  + (size_t)NTOK * DM;
        float* kb = qb + (size_t)NTOK * DM;
        float* vb = kb + (size_t)NTOK * DKV;
        float* yb = vb + (size_t)NTOK * DKV;
        float* gb = qb;
        float* ub = qb + (size_t)NTOK * IDIM;

        embed_kernel<<<NTOK, blk, 0, stream>>>(idx, embed, x);
        for (int l = 0; l < NLAY; l++) {
            rmsnorm_kernel<false><<<NTOK, blk, 0, stream>>>(x, ln1_w + (size_t)l * DM, h, nullptr, nullptr);
            gemm64_f32_kernel<false><<<dim3(10, NTOK/64), blk, 0, stream>>>(
                h, q_w + (size_t)l*DM*DM, k_w + (size_t)l*DM*DKV, v_w + (size_t)l*DM*DKV,
                qb, kb, vb, NTOK, DM, DM, DKV, DKV, 6, 2);
            rope_kernel<<<(NTOK*NH*32   + 255)/256, blk, 0, stream>>>(qb, NH,   NTOK*NH*32);
            rope_kernel<<<(NTOK*NKVH*32 + 255)/256, blk, 0, stream>>>(kb, NKVH, NTOK*NKVH*32);
            attn_kernel<false><<<2 * NH * (TSEQ/64), blk, 0, stream>>>(qb, kb, vb, yb, nullptr, nullptr);
            gemm64_f32_kernel<true><<<dim3(6, NTOK/64), blk, 0, stream>>>(
                yb, o_w + (size_t)l*DM*DM, nullptr, nullptr,
                x, nullptr, nullptr, NTOK, DM, DM, 0, 0, 6, 0);
            rmsnorm_kernel<false><<<NTOK, blk, 0, stream>>>(x, ln2_w + (size_t)l * DM, h, nullptr, nullptr);
            gemm64_f32_kernel<false><<<dim3(32, NTOK/64), blk, 0, stream>>>(
                h, gate_w + (size_t)l*DM*IDIM, up_w + (size_t)l*DM*IDIM, nullptr,
                gb, ub, nullptr, NTOK, DM, IDIM, IDIM, 0, 16, 16);
            silu_mul_kernel<false><<<(NTOK*IDIM + 255)/256, blk, 0, stream>>>(gb, ub, nullptr, nullptr, NTOK*IDIM);
            gemm64_f32_kernel<true><<<dim3(6, NTOK/64), blk, 0, stream>>>(
                gb, down_w + (size_t)l*IDIM*DM, nullptr, nullptr,
                x, nullptr, nullptr, NTOK, IDIM, DM, 0, 0, 6, 0);
        }
        rmsnorm_kernel<false><<<NTOK, blk, 0, stream>>>(x, norm_w, h, nullptr, nullptr);
        gemm_head_f32_kernel<<<dim3((VOC+127)/128, NTOK/128), blk, 0, stream>>>(h, embed, out, NTOK, VOC, DM);
    }
}